// Round 3
// baseline (74.235 us; speedup 1.0000x reference)
//
#include <hip/hip_runtime.h>

// Problem constants (B,N,D,E) = (8,1024,128,8)
constexpr int B_ = 8, N_ = 1024, D_ = 128, E_ = 8;
constexpr int ROWS = B_ * N_;   // 8192 flattened (b,s) rows

typedef __attribute__((ext_vector_type(8))) _Float16 f16x8;  // 8 f16 (4 VGPRs)
typedef __attribute__((ext_vector_type(4))) _Float16 f16x4;
typedef __attribute__((ext_vector_type(4))) float f32x4;     // MFMA accumulator

// ---------------------------------------------------------------------------
// Kernel 1 (unchanged): coef[bs][e] = sum_o adj[bs][o]*edge[bs][o][e]
// One block per (b,s) row; adj row in LDS; edge streamed as float4.
// ---------------------------------------------------------------------------
__global__ __launch_bounds__(256)
void coef_kernel(const float* __restrict__ edge,   // (ROWS, N, E)
                 const float* __restrict__ adj,    // (ROWS, N)
                 float* __restrict__ coef)         // (ROWS, E)
{
    __shared__ float s_adj[N_];
    __shared__ float s_red[4][2][4];
    const int bs  = blockIdx.x;
    const int tid = threadIdx.x;

    ((float4*)s_adj)[tid] = ((const float4*)(adj + (size_t)bs * N_))[tid];
    __syncthreads();

    const float4* e4 = (const float4*)(edge + (size_t)bs * N_ * E_);
    float acc[4] = {0.f, 0.f, 0.f, 0.f};
    #pragma unroll
    for (int it = 0; it < 8; ++it) {
        float4 ev = e4[it * 256 + tid];
        float a = s_adj[(it * 1024 + tid * 4) >> 3];
        acc[0] += a * ev.x; acc[1] += a * ev.y;
        acc[2] += a * ev.z; acc[3] += a * ev.w;
    }
    #pragma unroll
    for (int m = 2; m <= 32; m <<= 1) {
        acc[0] += __shfl_xor(acc[0], m, 64);
        acc[1] += __shfl_xor(acc[1], m, 64);
        acc[2] += __shfl_xor(acc[2], m, 64);
        acc[3] += __shfl_xor(acc[3], m, 64);
    }
    const int lane = tid & 63, wv = tid >> 6;
    if (lane < 2) {
        #pragma unroll
        for (int c = 0; c < 4; ++c) s_red[wv][lane][c] = acc[c];
    }
    __syncthreads();
    if (tid < 8) {
        const int h = tid >> 2, c = tid & 3;
        coef[(size_t)bs * E_ + tid] =
            s_red[0][h][c] + s_red[1][h][c] + s_red[2][h][c] + s_red[3][h][c];
    }
}

// ---------------------------------------------------------------------------
// Prep: Wh[e][i][j] = f16(W[e][i][j]).  131072 elems, 4/thread.
// ---------------------------------------------------------------------------
__global__ __launch_bounds__(256)
void wprep_kernel(const float* __restrict__ W, _Float16* __restrict__ Wh)
{
    const int i = blockIdx.x * 256 + threadIdx.x;     // 32768 threads
    float4 v = ((const float4*)W)[i];
    f16x4 h;
    h[0] = (_Float16)v.x; h[1] = (_Float16)v.y;
    h[2] = (_Float16)v.z; h[3] = (_Float16)v.w;
    ((f16x4*)Wh)[i] = h;
}

// ---------------------------------------------------------------------------
// Kernel 2 v3: out = A @ Wf  (8192 x 128, K = 1024 = e*128 + j), f16 MFMA.
//   A[r, e*128+j] = coef[r,e] * node[r,j]   (built in registers)
//   Wf[e*128+j, i] = Wh[e][i][j]            (direct f16x8 loads, L2-resident)
// Block = 512 threads = 8 waves, tile 16 rows x 128 cols; wave w owns cols
// [16w, 16w+16), one accumulator, 32 MFMA, fully unrolled.
// Grid = 512 blocks -> 2 blocks/CU, 16 waves/CU = 4 waves/SIMD.
// coef row hoisted out of the K-loop (2 x float4).
// ---------------------------------------------------------------------------
__global__ __launch_bounds__(512)
void gemm_kernel(const float* __restrict__ node,   // (ROWS, D)
                 const float* __restrict__ coef,   // (ROWS, E)
                 const _Float16* __restrict__ Wh,  // (E, D, D)
                 float* __restrict__ out)          // (ROWS, D)
{
    const int tid  = threadIdx.x;
    const int wv   = tid >> 6;           // col group 0..7
    const int lane = tid & 63;
    const int l16  = lane & 15;
    const int lk   = lane >> 4;          // k-group 0..3
    const int rbase = blockIdx.x * 16;
    const int cbase = 16 * wv;
    const int r = rbase + l16;           // A-row this lane supplies

    // Hoisted coef row (removes 8 serialized L2 trips from the K-loop)
    float cf[E_];
    {
        const float4* cp = (const float4*)(coef + (size_t)r * E_);
        float4 c0 = cp[0], c1 = cp[1];
        cf[0] = c0.x; cf[1] = c0.y; cf[2] = c0.z; cf[3] = c0.w;
        cf[4] = c1.x; cf[5] = c1.y; cf[6] = c1.z; cf[7] = c1.w;
    }

    // Preload this lane's x slices: xv[q][t] = x[q*32 + lk*8 + t]
    const float* xrow = node + (size_t)r * D_;
    float xv[4][8];
    #pragma unroll
    for (int q = 0; q < 4; ++q) {
        const float4* p = (const float4*)(xrow + q * 32 + lk * 8);
        float4 a = p[0], b = p[1];
        xv[q][0] = a.x; xv[q][1] = a.y; xv[q][2] = a.z; xv[q][3] = a.w;
        xv[q][4] = b.x; xv[q][5] = b.y; xv[q][6] = b.z; xv[q][7] = b.w;
    }

    f32x4 acc = {};

    #pragma unroll
    for (int e = 0; e < E_; ++e) {
        // B rows for this wave: i = cbase + l16; 4 lanes (lk) cover one 64B line
        const _Float16* We = Wh + (size_t)e * D_ * D_ + (size_t)(cbase + l16) * D_ + lk * 8;
        const float cfe = cf[e];
        #pragma unroll
        for (int js = 0; js < 4; ++js) {             // K-step of 32 within e
            f16x8 af;
            #pragma unroll
            for (int t = 0; t < 8; ++t) af[t] = (_Float16)(cfe * xv[js][t]);
            f16x8 bf = *(const f16x8*)(We + js * 32);
            acc = __builtin_amdgcn_mfma_f32_16x16x32_f16(af, bf, acc, 0, 0, 0);
        }
    }
    // C/D layout: col = lane&15, row = (lane>>4)*4 + reg
    const int col = cbase + l16;
    #pragma unroll
    for (int t = 0; t < 4; ++t) {
        out[(size_t)(rbase + lk * 4 + t) * D_ + col] = acc[t];
    }
}

extern "C" void kernel_launch(void* const* d_in, const int* in_sizes, int n_in,
                              void* d_out, int out_size, void* d_ws, size_t ws_size,
                              hipStream_t stream) {
    (void)in_sizes; (void)n_in; (void)out_size; (void)ws_size;
    const float* node = (const float*)d_in[0];   // (8,1024,128)
    const float* edge = (const float*)d_in[1];   // (8,1024,1024,8)
    const float* adj  = (const float*)d_in[2];   // (8,1024,1024)
    const float* W    = (const float*)d_in[3];   // (8,128,128)

    float*     coef = (float*)d_ws;                        // 256 KB
    _Float16*  Wh   = (_Float16*)((char*)d_ws + 256*1024); // 256 KB

    wprep_kernel<<<128, 256, 0, stream>>>(W, Wh);
    coef_kernel<<<ROWS, 256, 0, stream>>>(edge, adj, coef);
    gemm_kernel<<<ROWS / 16, 512, 0, stream>>>(node, coef, Wh, (float*)d_out);
}

// Round 4
// 60.125 us; speedup vs baseline: 1.2347x; 1.2347x over previous
//
#include <hip/hip_runtime.h>

// Problem constants (B,N,D,E) = (8,1024,128,8)
constexpr int B_ = 8, N_ = 1024, D_ = 128, E_ = 8;
constexpr int ROWS = B_ * N_;   // 8192 flattened (b,s) rows

typedef __attribute__((ext_vector_type(8))) _Float16 f16x8;  // 8 f16 (4 VGPRs)
typedef __attribute__((ext_vector_type(4))) _Float16 f16x4;
typedef __attribute__((ext_vector_type(4))) float f32x4;     // MFMA accumulator

// ---------------------------------------------------------------------------
// Kernel A: fused coef + W->f16 prep.
//  blocks [0, 4096): coef for rows {2*blk, 2*blk+1}, one row per wave.
//    coef[row][e] = sum_o adj[row][o] * edge[row][o][e]
//    Each lane streams 32 float4 (512 B) of the edge row; adj row in LDS.
//  blocks [4096, 4128): Wh[e][i][j] = f16(W[e][i][j])  (linear layout).
// ---------------------------------------------------------------------------
__global__ __launch_bounds__(128)
void coef_wprep_kernel(const float* __restrict__ edge,   // (ROWS, N, E)
                       const float* __restrict__ adj,    // (ROWS, N)
                       const float* __restrict__ W,      // (E, D, D)
                       float* __restrict__ coef,         // (ROWS, E)
                       _Float16* __restrict__ Wh)        // (E, D, D)
{
    const int blk = blockIdx.x;
    const int tid = threadIdx.x;

    if (blk >= ROWS / 2) {
        // --- wprep role: 32 blocks x 128 threads x 8 float4 = 32768 float4
        const int b = blk - ROWS / 2;
        #pragma unroll
        for (int q = 0; q < 8; ++q) {
            const int i = b * 1024 + q * 128 + tid;
            float4 v = ((const float4*)W)[i];
            f16x4 h;
            h[0] = (_Float16)v.x; h[1] = (_Float16)v.y;
            h[2] = (_Float16)v.z; h[3] = (_Float16)v.w;
            ((f16x4*)Wh)[i] = h;
        }
        return;
    }

    __shared__ float s_adj[2][N_];
    const int wv   = tid >> 6;
    const int lane = tid & 63;
    const int row  = blk * 2 + wv;

    // stage this wave's adj row: 256 float4 / 64 lanes = 4 each
    {
        const float4* ap = (const float4*)(adj + (size_t)row * N_);
        float4* sp = (float4*)s_adj[wv];
        #pragma unroll
        for (int q = 0; q < 4; ++q) sp[q * 64 + lane] = ap[q * 64 + lane];
    }
    __syncthreads();

    // stream edge row: float4 f covers o = f/2, e-half = f&1 (= lane&1)
    const float4* e4 = (const float4*)(edge + (size_t)row * N_ * E_);
    float ax = 0.f, ay = 0.f, az = 0.f, aw = 0.f;
    #pragma unroll 8
    for (int i = 0; i < 32; ++i) {
        float4 ev = e4[i * 64 + lane];
        float a = s_adj[wv][(i * 64 + lane) >> 1];
        ax += a * ev.x; ay += a * ev.y; az += a * ev.z; aw += a * ev.w;
    }
    // reduce over lanes, preserving parity bit 0 (e-half)
    #pragma unroll
    for (int m = 2; m <= 32; m <<= 1) {
        ax += __shfl_xor(ax, m, 64);
        ay += __shfl_xor(ay, m, 64);
        az += __shfl_xor(az, m, 64);
        aw += __shfl_xor(aw, m, 64);
    }
    if (lane < 2) {   // lane 0 -> e0..3, lane 1 -> e4..7
        float4 r; r.x = ax; r.y = ay; r.z = az; r.w = aw;
        ((float4*)(coef + (size_t)row * E_))[lane] = r;
    }
}

// ---------------------------------------------------------------------------
// Kernel B: out = A @ Wf  (8192 x 128, K = 1024 = e*128 + j), f16 MFMA.
// Block = 512 thr = 8 waves; tile 128 rows x 16 cols. Grid = 64 rblk x 8 cblk.
// The block's B-slice Wh[e][cbase+i16][j] (32 KB) is reg-staged into LDS with
// XOR swizzle (byte ^= (row&7)<<4 -> <=2-way bank conflicts, free) and reused
// by all 8 row-tiles: Wh L2/L3 traffic 128 MB -> 16 MB.
// cblk = bid&7 aligns with the XCD round-robin -> one slice resident per XCD.
// ---------------------------------------------------------------------------
__global__ __launch_bounds__(512)
void gemm_kernel(const float* __restrict__ node,   // (ROWS, D)
                 const float* __restrict__ coef,   // (ROWS, E)
                 const _Float16* __restrict__ Wh,  // (E, D, D)
                 float* __restrict__ out)          // (ROWS, D)
{
    __shared__ _Float16 sW[E_ * 16 * D_];   // 32 KB, [e][i16][j], swizzled
    const int tid  = threadIdx.x;
    const int cblk = blockIdx.x & 7;
    const int rblk = blockIdx.x >> 3;
    const int cbase = cblk * 16;

    // --- stage B-slice: thread -> 32 consecutive f16 (4 x 16B), swizzled write
    {
        const int lin = tid * 32;                 // f16 index within slice
        const int e   = lin >> 11;
        const int rem = lin & 2047;
        const int i16 = rem >> 7;
        const int j   = rem & 127;
        const _Float16* gp = Wh + ((size_t)e * D_ + (cbase + i16)) * D_ + j;
        char* lp = (char*)sW;
        const int xr = (i16 & 7) << 4;
        #pragma unroll
        for (int q = 0; q < 4; ++q) {
            f16x8 v = *(const f16x8*)(gp + q * 8);
            *(f16x8*)(lp + ((lin * 2 + q * 16) ^ xr)) = v;
        }
    }

    const int wv   = tid >> 6;          // row-tile 0..7
    const int lane = tid & 63;
    const int l16  = lane & 15;
    const int lk   = lane >> 4;         // k-group 0..3
    const int rbase = rblk * 128 + wv * 16;
    const int r = rbase + l16;

    // hoisted coef row
    float cf[E_];
    {
        const float4* cp = (const float4*)(coef + (size_t)r * E_);
        float4 c0 = cp[0], c1 = cp[1];
        cf[0] = c0.x; cf[1] = c0.y; cf[2] = c0.z; cf[3] = c0.w;
        cf[4] = c1.x; cf[5] = c1.y; cf[6] = c1.z; cf[7] = c1.w;
    }
    // preload x slices: xv[q][t] = x[q*32 + lk*8 + t]
    const float* xrow = node + (size_t)r * D_;
    float xv[4][8];
    #pragma unroll
    for (int q = 0; q < 4; ++q) {
        const float4* p = (const float4*)(xrow + q * 32 + lk * 8);
        float4 a = p[0], b = p[1];
        xv[q][0] = a.x; xv[q][1] = a.y; xv[q][2] = a.z; xv[q][3] = a.w;
        xv[q][4] = b.x; xv[q][5] = b.y; xv[q][6] = b.z; xv[q][7] = b.w;
    }

    __syncthreads();   // sW ready

    f32x4 acc = {};
    const int xr = (l16 & 7) << 4;
    #pragma unroll
    for (int e = 0; e < E_; ++e) {
        const float cfe = cf[e];
        #pragma unroll
        for (int js = 0; js < 4; ++js) {
            f16x8 af;
            #pragma unroll
            for (int t = 0; t < 8; ++t) af[t] = (_Float16)(cfe * xv[js][t]);
            const int boff = (((e * 16 + l16) * D_ + js * 32 + lk * 8) * 2) ^ xr;
            f16x8 bf = *(const f16x8*)((const char*)sW + boff);
            acc = __builtin_amdgcn_mfma_f32_16x16x32_f16(af, bf, acc, 0, 0, 0);
        }
    }
    // C/D layout: col = lane&15, row = (lane>>4)*4 + reg
    const int col = cbase + l16;
    #pragma unroll
    for (int t = 0; t < 4; ++t) {
        out[(size_t)(rbase + lk * 4 + t) * D_ + col] = acc[t];
    }
}

extern "C" void kernel_launch(void* const* d_in, const int* in_sizes, int n_in,
                              void* d_out, int out_size, void* d_ws, size_t ws_size,
                              hipStream_t stream) {
    (void)in_sizes; (void)n_in; (void)out_size; (void)ws_size;
    const float* node = (const float*)d_in[0];   // (8,1024,128)
    const float* edge = (const float*)d_in[1];   // (8,1024,1024,8)
    const float* adj  = (const float*)d_in[2];   // (8,1024,1024)
    const float* W    = (const float*)d_in[3];   // (8,128,128)

    float*     coefp = (float*)d_ws;                        // 256 KB
    _Float16*  Wh    = (_Float16*)((char*)d_ws + 256*1024); // 256 KB

    coef_wprep_kernel<<<ROWS / 2 + 32, 128, 0, stream>>>(edge, adj, W, coefp, Wh);
    gemm_kernel<<<(ROWS / 128) * 8, 512, 0, stream>>>(node, coefp, Wh, (float*)d_out);
}